// Round 5
// baseline (40.029 us; speedup 1.0000x reference)
//
#include <hip/hip_runtime.h>
#include <math.h>

#define BB 32
#define LL 512
#define DD 1024
#define TT 256
#define NK 136393      // total kept (s,e) pairs per batch
#define NK_LIN 131273  // offset(502) = 502*523/2
#define S_LIN 502
#define NEG_BIG  -3.0e38f   // finite stand-in for -inf in output
#define NEG_MASK -1.0e30f   // finite stand-in for masked logits
#define NRANGE 16
#define MAXROWS 64          // max rows per block = 51 + 10 halo = 61

typedef float f4v __attribute__((ext_vector_type(4)));
typedef float f2v __attribute__((ext_vector_type(2)));

// Split points equalizing per-block traffic: 4KB*rows + 12B*outputs ~= 290KB.
__device__ __constant__ int d_splits[NRANGE + 1] =
    {0, 51, 97, 138, 177, 212, 246, 277, 308, 336, 364, 391, 417, 441, 466, 489, 512};

__device__ __forceinline__ int off_s(int s) {
    return (s <= S_LIN) ? s * (s + 21) / 2 : NK_LIN + (s - S_LIN) * LL;
}

// One block = one (batch, s-range). Phase 1: GEMV logits for the range +10
// halo rows into LDS. Phase 2: emit scores+bounds for the range (LDS reads,
// nontemporal streaming stores). No intermediate global traffic, 1 dispatch.
__global__ __launch_bounds__(512, 4) void fused_kernel(
    const float* __restrict__ text, const float* __restrict__ W,
    const float* __restrict__ bias, const int* __restrict__ mask,
    const int* __restrict__ tmap, float* __restrict__ out)
{
    __shared__ float sl[MAXROWS], el[MAXROWS], ml[MAXROWS];
    __shared__ unsigned char tsl[LL], tel[LL];

    // physical->logical: 64 consecutive blocks per XCD; each XCD owns 4
    // batches so adjacent ranges (halo overlap) share an L2.
    const int p    = blockIdx.x;
    const int xcd  = p & 7, slot = p >> 3;
    const int bb   = xcd * 4 + (slot >> 4);
    const int ri   = slot & 15;
    const int a    = d_splits[ri], bnd = d_splits[ri + 1];
    const int rows_end = min(LL, bnd + 10);
    const int nrows    = rows_end - a;

    const int t = threadIdx.x;
    const int wid = t >> 6, lane = t & 63;

    tsl[t] = 0; tel[t] = 0;                       // 512 threads cover LL
    __syncthreads();
    if (t < TT) {
        int s0 = tmap[((size_t)bb * TT + t) * 2 + 0];
        int e0 = tmap[((size_t)bb * TT + t) * 2 + 1] - 1;
        s0 = min(max(s0, 0), LL - 1);
        e0 = min(max(e0, 0), LL - 1);
        tsl[s0] = 1;                              // benign race: all write 1
        tel[e0] = 1;
    }

    // Preload W fragments: lane's fi = lane + j*64 are row-invariant.
    f4v wreg[12];
#pragma unroll
    for (int j = 0; j < 4; ++j) {
        const int fi = lane + j * 64;
        wreg[j * 3 + 0] = ((const f4v*)W)[fi * 3 + 0];
        wreg[j * 3 + 1] = ((const f4v*)W)[fi * 3 + 1];
        wreg[j * 3 + 2] = ((const f4v*)W)[fi * 3 + 2];
    }
    const float b0 = bias[0], b1 = bias[1], b2 = bias[2];

    // ---- Phase 1: GEMV rows [a, rows_end), wave per row round-robin ----
    for (int r = wid; r < nrows; r += 8) {
        const int row = bb * LL + a + r;
        const f4v* t4 = (const f4v*)(text + (size_t)row * DD);
        float a0 = 0.f, a1 = 0.f, a2 = 0.f;
#pragma unroll
        for (int j = 0; j < 4; ++j) {
            f4v v  = __builtin_nontemporal_load(&t4[lane + j * 64]);
            f4v w0 = wreg[j * 3], w1 = wreg[j * 3 + 1], w2 = wreg[j * 3 + 2];
            a0 += v.x * w0.x;  a1 += v.x * w0.y;  a2 += v.x * w0.z;
            a0 += v.y * w0.w;  a1 += v.y * w1.x;  a2 += v.y * w1.y;
            a0 += v.z * w1.z;  a1 += v.z * w1.w;  a2 += v.z * w2.x;
            a0 += v.w * w2.y;  a1 += v.w * w2.z;  a2 += v.w * w2.w;
        }
#pragma unroll
        for (int o = 32; o; o >>= 1) {
            a0 += __shfl_down(a0, o);
            a1 += __shfl_down(a1, o);
            a2 += __shfl_down(a2, o);
        }
        if (lane == 0) {
            const int m = mask[row];
            sl[r] = (m == 1) ? a0 + b0 : NEG_MASK;
            el[r] = (m == 1) ? a1 + b1 : NEG_MASK;
            ml[r] = (m == 1) ? a2 + b2 : NEG_MASK;
        }
    }
    __syncthreads();

    // ---- Phase 2: emit rows [a, bnd): scores + bounds, streaming ----
    f2v* bptr = (f2v*)(out + (size_t)BB * NK);
    for (int r = wid; r < bnd - a; r += 8) {
        const int s = a + r;
        const int fss = (s != 0) && tsl[s] && (mask[bb * LL + s] == 1);
        const float sv = sl[r];
        const int rowlen = min(LL, s + 11);
        const size_t obase = (size_t)bb * NK + off_s(s);
        for (int c = 0; c * 64 < rowlen; ++c) {
            const int e = c * 64 + lane;
            if (e < rowlen) {
                float score = NEG_BIG;
                if (e >= s && fss && e != 0 && tel[e]) {
                    float w = 0.f;
                    for (int l = r; l <= e - a; ++l) w += ml[l];  // <=11 LDS reads
                    score = sv + el[e - a] + w;
                }
                __builtin_nontemporal_store(score, &out[obase + e]);
                f2v bv; bv.x = (float)s; bv.y = (float)e;
                __builtin_nontemporal_store(bv, &bptr[obase + e]);
            }
        }
    }
}

extern "C" void kernel_launch(void* const* d_in, const int* in_sizes, int n_in,
                              void* d_out, int out_size, void* d_ws, size_t ws_size,
                              hipStream_t stream) {
    const float* text = (const float*)d_in[0];   // (B,L,D) f32
    const int*   mask = (const int*)d_in[1];     // (B,L) i32
    const int*   tmap = (const int*)d_in[2];     // (B,T,2) i32
    const float* W    = (const float*)d_in[3];   // (D,3) f32
    const float* bias = (const float*)d_in[4];   // (3,) f32
    float* out = (float*)d_out;

    fused_kernel<<<BB * NRANGE, 512, 0, stream>>>(text, W, bias, mask, tmap, out);
}

// Round 6
// 29.223 us; speedup vs baseline: 1.3698x; 1.3698x over previous
//
#include <hip/hip_runtime.h>
#include <math.h>

#define BB 32
#define LL 512
#define DD 1024
#define TT 256
#define NK 136393              // kept (s,e) pairs per batch
#define NK_LIN 131273          // off(502)
#define S_LIN 502
#define NEG_BIG  -3.0e38f      // finite stand-in for -inf
#define NEG_MASK -1.0e30f      // finite stand-in for masked logits
#define P_TOT (BB * NK)        // 4364576 total pairs
#define FILL_THREADS (P_TOT / 4)               // 1091144 (P_TOT % 4 == 0)
#define FILL_BLOCKS ((FILL_THREADS + 255) / 256) // 4263
#define GEMV_BLOCKS (BB * LL / 4)              // 4096

typedef float f4v __attribute__((ext_vector_type(4)));

__device__ __forceinline__ int off_s(int s) {
    return (s <= S_LIN) ? s * (s + 21) / 2 : NK_LIN + (s - S_LIN) * LL;
}

// ---- Kernel 1 (mega): block-specialized fill | GEMV, one dispatch --------
// Fill blocks: stream constant scores (float4) + static bounds pattern
// (2x float4) = 48 B/thread, no flags, no gating -> fill-rate stores.
// GEMV blocks: wave per row, 4 KB contiguous/wave, regular loads (L3 reuse).
__global__ __launch_bounds__(256) void mega_kernel(
    const float* __restrict__ text, const float* __restrict__ W,
    const float* __restrict__ bias, const int* __restrict__ mask,
    float* __restrict__ out,
    float* __restrict__ slp, float* __restrict__ elp, float* __restrict__ mlp)
{
    if (blockIdx.x < FILL_BLOCKS) {
        const int i = blockIdx.x * 256 + threadIdx.x;
        if (i >= FILL_THREADS) return;
        const int idx = i * 4;                 // flat pair index (4 per thread)

        // scores: constant fill, 16B aligned (idx % 4 == 0)
        f4v neg = {NEG_BIG, NEG_BIG, NEG_BIG, NEG_BIG};
        *(f4v*)(out + idx) = neg;

        // bounds: (s,e) pattern repeats per batch; k = idx mod NK
        int k = idx - (idx / NK) * NK;
        int s, e;
        if (k >= NK_LIN) {
            const int r = k - NK_LIN;
            s = S_LIN + (r >> 9);
            e = r & 511;
        } else {
            float f = sqrtf(8.0f * (float)k + 441.0f);
            s = (int)((f - 21.0f) * 0.5f);
            if (s < 0) s = 0;
            if (s > 501) s = 501;
            while ((s + 1) * (s + 22) / 2 <= k) ++s;
            while (s * (s + 21) / 2 > k) --s;
            e = k - s * (s + 21) / 2;
        }
        float bs[8];
#pragma unroll
        for (int j = 0; j < 4; ++j) {
            bs[2 * j] = (float)s; bs[2 * j + 1] = (float)e;
            ++e;
            const int rowlen = (s <= S_LIN) ? (s + 11) : LL;  // min(LL, s+11)
            if (e >= rowlen) { e = 0; if (++s >= LL) s = 0; } // batch wrap: same pattern
        }
        f4v* bp = (f4v*)(out + (size_t)P_TOT + (size_t)2 * idx);
        f4v b0 = {bs[0], bs[1], bs[2], bs[3]};
        f4v b1 = {bs[4], bs[5], bs[6], bs[7]};
        bp[0] = b0; bp[1] = b1;
        return;
    }

    // ---- GEMV: logits = text @ W + b, one wave per row ----
    const int gb   = blockIdx.x - FILL_BLOCKS;
    const int wid  = threadIdx.x >> 6;
    const int lane = threadIdx.x & 63;
    const int row  = gb * 4 + wid;             // row = b*L + l in [0, 16384)

    const f4v* t4 = (const f4v*)(text + (size_t)row * DD);
    const f4v* w4 = (const f4v*)W;
    float a0 = 0.f, a1 = 0.f, a2 = 0.f;
#pragma unroll
    for (int j = 0; j < 4; ++j) {
        const int fi = lane + j * 64;
        f4v v  = t4[fi];                       // regular load: L3-resident reuse
        f4v w0 = w4[fi * 3 + 0];
        f4v w1 = w4[fi * 3 + 1];
        f4v w2 = w4[fi * 3 + 2];
        a0 += v.x * w0.x;  a1 += v.x * w0.y;  a2 += v.x * w0.z;
        a0 += v.y * w0.w;  a1 += v.y * w1.x;  a2 += v.y * w1.y;
        a0 += v.z * w1.z;  a1 += v.z * w1.w;  a2 += v.z * w2.x;
        a0 += v.w * w2.y;  a1 += v.w * w2.z;  a2 += v.w * w2.w;
    }
#pragma unroll
    for (int o = 32; o; o >>= 1) {
        a0 += __shfl_down(a0, o);
        a1 += __shfl_down(a1, o);
        a2 += __shfl_down(a2, o);
    }
    if (lane == 0) {
        const int m = mask[row];
        slp[row] = (m == 1) ? a0 + bias[0] : NEG_MASK;
        elp[row] = (m == 1) ? a1 + bias[1] : NEG_MASK;
        mlp[row] = (m == 1) ? a2 + bias[2] : NEG_MASK;
    }
}

// ---- Kernel 2: scatter valid scores (<= ~2.2K per batch) ------------------
__global__ __launch_bounds__(512) void scatter_kernel(
    const float* __restrict__ slp, const float* __restrict__ elp,
    const float* __restrict__ mlp, const int* __restrict__ mask,
    const int* __restrict__ tmap, float* __restrict__ out)
{
    const int b = blockIdx.x;
    const int t = threadIdx.x;
    __shared__ float sl[LL], el[LL], ml[LL];
    __shared__ unsigned char tsl[LL], tel[LL];

    tsl[t] = 0; tel[t] = 0;
    const int idx = b * LL + t;
    sl[t] = slp[idx]; el[t] = elp[idx]; ml[t] = mlp[idx];
    __syncthreads();
    if (t < TT) {
        int s0 = tmap[((size_t)b * TT + t) * 2 + 0];
        int e0 = tmap[((size_t)b * TT + t) * 2 + 1] - 1;
        s0 = min(max(s0, 0), LL - 1);
        e0 = min(max(e0, 0), LL - 1);
        tsl[s0] = 1;                           // benign race: all write 1
        tel[e0] = 1;
    }
    __syncthreads();

    const int s = t;
    if (s > 0 && tsl[s] && mask[idx] == 1) {
        const size_t obase = (size_t)b * NK + off_s(s);
        const float sv = sl[s];
        const int emax = min(LL - 1, s + 10);
        float w = 0.f;
        for (int e = s; e <= emax; ++e) {
            w += ml[e];
            if (tel[e]) {                      // e >= s >= 1, so e != 0
                float sc = sv + el[e] + w;
                if (sc < -1.0e29f) sc = NEG_BIG;   // masked e/l -> -inf in ref
                out[obase + e] = sc;
            }
        }
    }
}

extern "C" void kernel_launch(void* const* d_in, const int* in_sizes, int n_in,
                              void* d_out, int out_size, void* d_ws, size_t ws_size,
                              hipStream_t stream) {
    const float* text = (const float*)d_in[0];   // (B,L,D) f32
    const int*   mask = (const int*)d_in[1];     // (B,L) i32
    const int*   tmap = (const int*)d_in[2];     // (B,T,2) i32
    const float* W    = (const float*)d_in[3];   // (D,3) f32
    const float* bias = (const float*)d_in[4];   // (3,) f32
    float* out = (float*)d_out;

    float* slp = (float*)d_ws;                   // B*L each
    float* elp = slp + (size_t)BB * LL;
    float* mlp = elp + (size_t)BB * LL;

    mega_kernel<<<FILL_BLOCKS + GEMV_BLOCKS, 256, 0, stream>>>(
        text, W, bias, mask, out, slp, elp, mlp);
    scatter_kernel<<<BB, 512, 0, stream>>>(slp, elp, mlp, mask, tmap, out);
}